// Round 12
// baseline (187.743 us; speedup 1.0000x reference)
//
#include <hip/hip_runtime.h>
#include <hip/hip_cooperative_groups.h>

namespace cg = cooperative_groups;

#define BATCH 8
#define NN    256
#define FIN   128
#define H1    4
#define C1    128
#define HC1   512   // H1*C1
#define NEG_SLOPE 0.2f

__device__ __forceinline__ float lrelu(float v) {
    return v > 0.f ? v : NEG_SLOPE * v;
}

// Single cooperative kernel, 256 blocks x 512 threads (1 block/CU), 3 phases.
// LDS pool (floats), reused across phases:
//  P1: xs[8][128]@0, rS[8][8]@1024, rD[8][8]@1088
//  P2: s_as[4][256]@0, s_ad[4][8]@1024, spT[256][36]@1056, s_den[32]@10272,
//      hrelu[8][512]@10304, red[3][8][128]@14400, redS[8][2]@17472, redD[8][2]@17488
//  P3: s_as3[256]@0, s_ad3[8]@256, spT3[256][8]@272, den3[8]@2320, redA[3][8][128]@2336
#define POOL_FLOATS 17504

__global__ __launch_bounds__(512, 2)
void gat_all(const float* __restrict__ x,   const float* __restrict__ W1,
             const float* __restrict__ as1, const float* __restrict__ ad1,
             const float* __restrict__ b1,  const float* __restrict__ W2,
             const float* __restrict__ as2, const float* __restrict__ ad2,
             const float* __restrict__ b2,  float* __restrict__ out,
             float* __restrict__ h1, float* __restrict__ h2,
             float* __restrict__ aS1, float* __restrict__ aD1,
             float* __restrict__ aS2, float* __restrict__ aD2) {
    __shared__ __align__(16) float pool[POOL_FLOATS];
    cg::grid_group grid = cg::this_grid();
    const int blk = blockIdx.x, t = threadIdx.x;

    // ---------------- Phase 1: h1 = x @ W1 (+ ared1) ------------------------
    {
        float* xs = pool;                 // [8][128]
        float* rS = pool + 1024;          // [8][8]
        float* rD = pool + 1088;          // [8][8]
        const int b = blk >> 5, rt = blk & 31;     // 32 rowtiles of 8
        const float* xp = x + ((size_t)b * NN + rt * 8) * FIN;
        if (t < 256) ((float4*)xs)[t] = ((const float4*)xp)[t];
        __syncthreads();

        float acc[8] = {0,0,0,0,0,0,0,0};
        #pragma unroll 4
        for (int k = 0; k < FIN; ++k) {
            float w = W1[(size_t)k * HC1 + t];
            #pragma unroll
            for (int r = 0; r < 8; ++r)
                acc[r] = fmaf(xs[r * FIN + k], w, acc[r]);
        }
        #pragma unroll
        for (int r = 0; r < 8; ++r)
            h1[((size_t)b * NN + rt * 8 + r) * HC1 + t] = acc[r];

        const float as = as1[t], ad = ad1[t];
        const int w = t >> 6, lane = t & 63;
        #pragma unroll
        for (int r = 0; r < 8; ++r) {
            float s = acc[r] * as, d = acc[r] * ad;
            #pragma unroll
            for (int off = 32; off > 0; off >>= 1) {
                s += __shfl_down(s, off, 64);
                d += __shfl_down(d, off, 64);
            }
            if (lane == 0) { rS[r * 8 + w] = s; rD[r * 8 + w] = d; }
        }
        __syncthreads();
        if (t < 32) {   // wave w covers cols [64w,64w+63] -> head w>>1
            int r = t & 7, h = t >> 3;
            size_t node = (size_t)b * NN + rt * 8 + r;
            aS1[node * H1 + h] = rS[r * 8 + 2 * h] + rS[r * 8 + 2 * h + 1];
            aD1[node * H1 + h] = rD[r * 8 + 2 * h] + rD[r * 8 + 2 * h + 1];
        }
    }
    grid.sync();

    // ---------------- Phase 2: agg1(all heads)+relu+gemm2+ared2 -------------
    {
        float* s_as  = pool;              // [4][256]
        float* s_ad  = pool + 1024;       // [4][8]
        float* spT   = pool + 1056;       // [256][36]
        float* s_den = pool + 10272;      // [32]
        float* hrelu = pool + 10304;      // [8][512]
        float* red   = pool + 14400;      // [3][8][128]
        float* redS  = pool + 17472;      // [8][2]
        float* redD  = pool + 17488;      // [8][2]
        const int b = blk >> 5, d0 = (blk & 31) * 8;

        {
            int i0 = t, i1 = t + 512;     // 1024 = 4 heads * 256 nodes
            s_as[(i0 >> 8) * NN + (i0 & 255)] =
                aS1[((size_t)b * NN + (i0 & 255)) * H1 + (i0 >> 8)];
            s_as[(i1 >> 8) * NN + (i1 & 255)] =
                aS1[((size_t)b * NN + (i1 & 255)) * H1 + (i1 >> 8)];
            if (t < 32) {
                int h = t >> 3, d = t & 7;
                s_ad[h * 8 + d] = aD1[((size_t)b * NN + d0 + d) * H1 + h];
            }
        }
        __syncthreads();

        // softmax: 32 (head,dst) pairs x 16 threads; each thread 16 srcs.
        {
            const int pair = t >> 4, sub = t & 15;
            const int h = pair >> 3, d = pair & 7;
            const float adst = s_ad[h * 8 + d];
            float e[16];
            float mx = -1e30f;
            #pragma unroll
            for (int i = 0; i < 16; ++i) {
                float v = lrelu(s_as[h * NN + sub + i * 16] + adst);
                e[i] = v;
                mx = fmaxf(mx, v);
            }
            #pragma unroll
            for (int off = 8; off > 0; off >>= 1)
                mx = fmaxf(mx, __shfl_down(mx, off, 16));
            mx = __shfl(mx, 0, 16);
            float sum = 0.f;
            #pragma unroll
            for (int i = 0; i < 16; ++i) {
                float p = __expf(e[i] - mx);
                spT[(sub + i * 16) * 36 + pair] = p;
                sum += p;
            }
            #pragma unroll
            for (int off = 8; off > 0; off >>= 1)
                sum += __shfl_down(sum, off, 16);
            if (sub == 0) s_den[pair] = sum + 1e-16f;
        }
        __syncthreads();

        // agg1: thread t -> col t (h = t>>7); 8 dsts; coalesced h1 load per src.
        {
            const int ct = t, h = t >> 7;
            float acc8[8] = {0,0,0,0,0,0,0,0};
            const float* hb = h1 + (size_t)(b * NN) * HC1 + ct;
            #pragma unroll 4
            for (int src = 0; src < NN; ++src) {
                float hv = hb[(size_t)src * HC1];
                float4 pa = *(const float4*)&spT[src * 36 + h * 8];
                float4 pb = *(const float4*)&spT[src * 36 + h * 8 + 4];
                acc8[0] = fmaf(pa.x, hv, acc8[0]);
                acc8[1] = fmaf(pa.y, hv, acc8[1]);
                acc8[2] = fmaf(pa.z, hv, acc8[2]);
                acc8[3] = fmaf(pa.w, hv, acc8[3]);
                acc8[4] = fmaf(pb.x, hv, acc8[4]);
                acc8[5] = fmaf(pb.y, hv, acc8[5]);
                acc8[6] = fmaf(pb.z, hv, acc8[6]);
                acc8[7] = fmaf(pb.w, hv, acc8[7]);
            }
            const float bias = b1[ct];
            #pragma unroll
            for (int d = 0; d < 8; ++d)
                hrelu[d * HC1 + ct] =
                    fmaxf(acc8[d] / s_den[h * 8 + d] + bias, 0.f);
        }
        __syncthreads();

        // gemm2: K split 4-way (g); 8 rows x 128 cols; float4 LDS reads.
        const int c2 = t & 127, g = t >> 7;
        float acc[8] = {0,0,0,0,0,0,0,0};
        {
            const float* wb = W2 + (size_t)(g * 128) * FIN + c2;
            #pragma unroll 2
            for (int kq = 0; kq < 32; ++kq) {
                float w0 = wb[(size_t)(kq * 4 + 0) * FIN];
                float w1 = wb[(size_t)(kq * 4 + 1) * FIN];
                float w2 = wb[(size_t)(kq * 4 + 2) * FIN];
                float w3 = wb[(size_t)(kq * 4 + 3) * FIN];
                #pragma unroll
                for (int r = 0; r < 8; ++r) {
                    float4 xv = *(const float4*)&hrelu[r * HC1 + g * 128 + kq * 4];
                    acc[r] = fmaf(xv.x, w0, acc[r]);
                    acc[r] = fmaf(xv.y, w1, acc[r]);
                    acc[r] = fmaf(xv.z, w2, acc[r]);
                    acc[r] = fmaf(xv.w, w3, acc[r]);
                }
            }
        }
        if (g > 0) {
            #pragma unroll
            for (int r = 0; r < 8; ++r) red[(g - 1) * 1024 + r * 128 + c2] = acc[r];
        }
        __syncthreads();
        if (g == 0) {
            #pragma unroll
            for (int r = 0; r < 8; ++r) {
                acc[r] += red[r * 128 + c2] + red[1024 + r * 128 + c2]
                        + red[2048 + r * 128 + c2];
                h2[((size_t)b * NN + d0 + r) * FIN + c2] = acc[r];
            }
            const int lane = t & 63, wv = t >> 6;
            const float asv = as2[c2], adv = ad2[c2];
            #pragma unroll
            for (int r = 0; r < 8; ++r) {
                float s = acc[r] * asv, dd = acc[r] * adv;
                #pragma unroll
                for (int off = 32; off > 0; off >>= 1) {
                    s += __shfl_down(s, off, 64);
                    dd += __shfl_down(dd, off, 64);
                }
                if (lane == 0) { redS[r * 2 + wv] = s; redD[r * 2 + wv] = dd; }
            }
        }
        __syncthreads();
        if (t < 8) {
            aS2[(size_t)b * NN + d0 + t] = redS[t * 2] + redS[t * 2 + 1];
            aD2[(size_t)b * NN + d0 + t] = redD[t * 2] + redD[t * 2 + 1];
        }
    }
    grid.sync();

    // ---------------- Phase 3: layer-2 softmax + aggregate + bias -----------
    {
        float* s_as3 = pool;              // [256]
        float* s_ad3 = pool + 256;        // [8]
        float* spT3  = pool + 272;        // [256][8]
        float* den3  = pool + 2320;       // [8]
        float* redA  = pool + 2336;       // [3][8][128]
        const int b = blk >> 5, d0 = (blk & 31) * 8;

        if (t < NN) s_as3[t] = aS2[(size_t)b * NN + t];
        if (t < 8)  s_ad3[t] = aD2[(size_t)b * NN + d0 + t];
        __syncthreads();

        // softmax: one wave (64 lanes) per dst; each lane 4 srcs.
        {
            const int d = t >> 6, lane = t & 63;
            const float adst = s_ad3[d];
            float e[4];
            float mx = -1e30f;
            #pragma unroll
            for (int i = 0; i < 4; ++i) {
                float v = lrelu(s_as3[lane + i * 64] + adst);
                e[i] = v;
                mx = fmaxf(mx, v);
            }
            #pragma unroll
            for (int off = 32; off > 0; off >>= 1)
                mx = fmaxf(mx, __shfl_down(mx, off, 64));
            mx = __shfl(mx, 0, 64);
            float sum = 0.f;
            #pragma unroll
            for (int i = 0; i < 4; ++i) {
                float p = __expf(e[i] - mx);
                spT3[(lane + i * 64) * 8 + d] = p;
                sum += p;
            }
            #pragma unroll
            for (int off = 32; off > 0; off >>= 1)
                sum += __shfl_down(sum, off, 64);
            if (lane == 0) den3[d] = sum + 1e-16f;
        }
        __syncthreads();

        // aggregation: q = src-quarter, c = col; 8 dsts per thread.
        const int c = t & 127, q = t >> 7;
        float acc8[8] = {0,0,0,0,0,0,0,0};
        const float* hb = h2 + ((size_t)b * NN + q * 64) * FIN + c;
        #pragma unroll 4
        for (int i = 0; i < 64; ++i) {
            float hv = hb[(size_t)i * FIN];
            float4 pa = *(const float4*)&spT3[(q * 64 + i) * 8];
            float4 pb = *(const float4*)&spT3[(q * 64 + i) * 8 + 4];
            acc8[0] = fmaf(pa.x, hv, acc8[0]);
            acc8[1] = fmaf(pa.y, hv, acc8[1]);
            acc8[2] = fmaf(pa.z, hv, acc8[2]);
            acc8[3] = fmaf(pa.w, hv, acc8[3]);
            acc8[4] = fmaf(pb.x, hv, acc8[4]);
            acc8[5] = fmaf(pb.y, hv, acc8[5]);
            acc8[6] = fmaf(pb.z, hv, acc8[6]);
            acc8[7] = fmaf(pb.w, hv, acc8[7]);
        }
        if (q > 0) {
            #pragma unroll
            for (int j = 0; j < 8; ++j) redA[(q - 1) * 1024 + j * 128 + c] = acc8[j];
        }
        __syncthreads();
        if (q == 0) {
            const float bias = b2[c];
            #pragma unroll
            for (int j = 0; j < 8; ++j) {
                float v = acc8[j] + redA[j * 128 + c] + redA[1024 + j * 128 + c]
                        + redA[2048 + j * 128 + c];
                out[((size_t)b * NN + d0 + j) * FIN + c] = v / den3[j] + bias;
            }
        }
    }
}

// ---------------- launch -----------------------------------------------------
extern "C" void kernel_launch(void* const* d_in, const int* in_sizes, int n_in,
                              void* d_out, int out_size, void* d_ws, size_t ws_size,
                              hipStream_t stream) {
    const float* x   = (const float*)d_in[0];
    const float* W1  = (const float*)d_in[1];
    const float* as1 = (const float*)d_in[2];
    const float* ad1 = (const float*)d_in[3];
    const float* b1  = (const float*)d_in[4];
    const float* W2  = (const float*)d_in[5];
    const float* as2 = (const float*)d_in[6];
    const float* ad2 = (const float*)d_in[7];
    const float* b2  = (const float*)d_in[8];
    float* out = (float*)d_out;

    float* ws = (float*)d_ws;
    float* h1  = ws;                      // 8*256*512 = 1048576
    float* h2  = ws + 1048576;            // 262144
    float* aS1 = ws + 1310720;            // 8192
    float* aD1 = ws + 1318912;            // 8192
    float* aS2 = ws + 1327104;            // 2048
    float* aD2 = ws + 1329152;            // 2048

    void* args[] = {
        (void*)&x, (void*)&W1, (void*)&as1, (void*)&ad1, (void*)&b1,
        (void*)&W2, (void*)&as2, (void*)&ad2, (void*)&b2, (void*)&out,
        (void*)&h1, (void*)&h2, (void*)&aS1, (void*)&aD1, (void*)&aS2, (void*)&aD2
    };
    hipLaunchCooperativeKernel((const void*)gat_all, dim3(256), dim3(512),
                               args, 0, stream);
}

// Round 14
// 113.938 us; speedup vs baseline: 1.6478x; 1.6478x over previous
//
#include <hip/hip_runtime.h>
#include <hip/hip_bf16.h>

#define BATCH 8
#define NN    256
#define FIN   128
#define H1    4
#define C1    128
#define HC1   512   // H1*C1
#define NEG_SLOPE 0.2f

__device__ __forceinline__ float lrelu(float v) {
    return v > 0.f ? v : NEG_SLOPE * v;
}

// All kernels: 1D grid of 512 blocks, batch = blk & 7 -> round-robin XCD
// assignment pins each batch's h1/h2 to one XCD's L2 (writer==reader XCD).

// ---------------- K1: h1 = x @ W1, fused a_src1/a_dst1 ----------------------
// 512 blocks x 512 thr (4 waves/SIMD). Block: 4 rows x 512 cols, 4 FMA/load.
__global__ __launch_bounds__(512, 4)
void gemm1_fused(const float* __restrict__ x, const float* __restrict__ W1,
                 const float* __restrict__ as1, const float* __restrict__ ad1,
                 float* __restrict__ h1, float* __restrict__ a_src,
                 float* __restrict__ a_dst) {
    __shared__ float xs[4][FIN];
    __shared__ float redS[4][8], redD[4][8];
    const int blk = blockIdx.x, t = threadIdx.x;
    const int b = blk & 7, r0 = (blk >> 3) * 4;

    if (t < 128)   // 4 rows x 128 = 128 float4, coalesced
        ((float4*)xs)[t] = ((const float4*)(x + (size_t)(b * NN + r0) * FIN))[t];
    __syncthreads();

    float a0 = 0.f, a1 = 0.f, a2 = 0.f, a3 = 0.f;
    #pragma unroll 8
    for (int k = 0; k < FIN; ++k) {
        float w = W1[k * HC1 + t];
        a0 = fmaf(xs[0][k], w, a0);
        a1 = fmaf(xs[1][k], w, a1);
        a2 = fmaf(xs[2][k], w, a2);
        a3 = fmaf(xs[3][k], w, a3);
    }
    float acc[4] = {a0, a1, a2, a3};
    #pragma unroll
    for (int r = 0; r < 4; ++r)
        h1[(b * NN + r0 + r) * HC1 + t] = acc[r];

    // fused a-reductions: col t -> head t>>7; att vectors are flat [512].
    const float as = as1[t], ad = ad1[t];
    const int w = t >> 6, lane = t & 63;
    #pragma unroll
    for (int r = 0; r < 4; ++r) {
        float s = acc[r] * as, d = acc[r] * ad;
        #pragma unroll
        for (int off = 32; off > 0; off >>= 1) {
            s += __shfl_down(s, off, 64);
            d += __shfl_down(d, off, 64);
        }
        if (lane == 0) { redS[r][w] = s; redD[r][w] = d; }
    }
    __syncthreads();
    if (t < 16) {   // wave w covers cols [64w,64w+63] -> head w>>1
        int r = t & 3, h = t >> 2;
        a_src[(b * NN + r0 + r) * H1 + h] = redS[r][2 * h] + redS[r][2 * h + 1];
        a_dst[(b * NN + r0 + r) * H1 + h] = redD[r][2 * h] + redD[r][2 * h + 1];
    }
}

// ---------------- K2: agg1(all heads)+relu+gemm2+ared2 fused ----------------
// 512 blocks x 512 thr; 4 dsts/block; hrelu never leaves LDS. LDS ~38 KB.
__global__ __launch_bounds__(512, 4)
void mid_fused(const float* __restrict__ h1, const float* __restrict__ a_src,
               const float* __restrict__ a_dst, const float* __restrict__ b1,
               const float* __restrict__ W2, const float* __restrict__ as2,
               const float* __restrict__ ad2, float* __restrict__ h2,
               float* __restrict__ a_src2, float* __restrict__ a_dst2) {
    __shared__ __align__(16) float s_as[H1][NN];      // 4 KB
    __shared__ float s_ad[H1][4];
    __shared__ __align__(16) float spT[NN][20];       // 20 KB: p[src][h*4+d], stride 20
    __shared__ float s_den[16];
    __shared__ __align__(16) float hrelu_s[4][HC1];   // 8 KB
    __shared__ float red[3][4][FIN];                  // 6 KB
    __shared__ float redS[4][2], redD[4][2];

    const int blk = blockIdx.x, t = threadIdx.x;
    const int b = blk & 7, d0 = (blk >> 3) * 4;

    {   // stage a_src (4 heads x 256 nodes) and a_dst (4 dsts x 4 heads)
        int i0 = t, i1 = t + 512;                     // 1024 = 4*256
        ((float*)s_as)[(i0 >> 8) * NN + (i0 & 255)] =
            a_src[((size_t)b * NN + (i0 & 255)) * H1 + (i0 >> 8)];
        ((float*)s_as)[(i1 >> 8) * NN + (i1 & 255)] =
            a_src[((size_t)b * NN + (i1 & 255)) * H1 + (i1 >> 8)];
        if (t < 16) {
            int h = t >> 2, d = t & 3;
            s_ad[h][d] = a_dst[((size_t)b * NN + d0 + d) * H1 + h];
        }
    }
    __syncthreads();

    // softmax: 16 (head,dst) pairs x 32 threads; each thread 8 srcs.
    {
        const int pair = t >> 5, sub = t & 31;
        const int h = pair >> 2, d = pair & 3;
        const float adst = s_ad[h][d];
        float e[8];
        float mx = -1e30f;
        #pragma unroll
        for (int i = 0; i < 8; ++i) {
            float v = lrelu(s_as[h][sub + i * 32] + adst);
            e[i] = v;
            mx = fmaxf(mx, v);
        }
        #pragma unroll
        for (int off = 16; off > 0; off >>= 1)
            mx = fmaxf(mx, __shfl_down(mx, off, 32));
        mx = __shfl(mx, 0, 32);
        float sum = 0.f;
        #pragma unroll
        for (int i = 0; i < 8; ++i) {
            float p = __expf(e[i] - mx);
            spT[sub + i * 32][pair] = p;
            sum += p;
        }
        #pragma unroll
        for (int off = 16; off > 0; off >>= 1)
            sum += __shfl_down(sum, off, 32);
        if (sub == 0) s_den[pair] = sum + 1e-16f;
    }
    __syncthreads();

    // agg1: thread t -> col t (h = t>>7); 4 dsts; coalesced h1 load per src.
    {
        const int ct = t, h = t >> 7;
        float acc4[4] = {0, 0, 0, 0};
        const float* hb = h1 + (size_t)(b * NN) * HC1 + ct;
        #pragma unroll 4
        for (int src = 0; src < NN; ++src) {
            float hv = hb[(size_t)src * HC1];
            float4 pa = *(const float4*)&spT[src][h * 4];
            acc4[0] = fmaf(pa.x, hv, acc4[0]);
            acc4[1] = fmaf(pa.y, hv, acc4[1]);
            acc4[2] = fmaf(pa.z, hv, acc4[2]);
            acc4[3] = fmaf(pa.w, hv, acc4[3]);
        }
        const float bias = b1[ct];
        #pragma unroll
        for (int d = 0; d < 4; ++d)
            hrelu_s[d][ct] = fmaxf(acc4[d] / s_den[h * 4 + d] + bias, 0.f);
    }
    __syncthreads();

    // gemm2: K split 4-way (g); 4 rows x 128 cols; float4 LDS reads.
    const int c2 = t & 127, g = t >> 7;
    float acc[4] = {0, 0, 0, 0};
    {
        const float* wb = W2 + (size_t)(g * 128) * FIN + c2;
        #pragma unroll 4
        for (int kq = 0; kq < 32; ++kq) {
            float w0 = wb[(size_t)(kq * 4 + 0) * FIN];
            float w1 = wb[(size_t)(kq * 4 + 1) * FIN];
            float w2 = wb[(size_t)(kq * 4 + 2) * FIN];
            float w3 = wb[(size_t)(kq * 4 + 3) * FIN];
            #pragma unroll
            for (int r = 0; r < 4; ++r) {
                float4 xv = *(const float4*)&hrelu_s[r][g * 128 + kq * 4];
                acc[r] = fmaf(xv.x, w0, acc[r]);
                acc[r] = fmaf(xv.y, w1, acc[r]);
                acc[r] = fmaf(xv.z, w2, acc[r]);
                acc[r] = fmaf(xv.w, w3, acc[r]);
            }
        }
    }
    if (g > 0) {
        #pragma unroll
        for (int r = 0; r < 4; ++r) red[g - 1][r][c2] = acc[r];
    }
    __syncthreads();
    if (g == 0) {
        #pragma unroll
        for (int r = 0; r < 4; ++r) {
            acc[r] += red[0][r][c2] + red[1][r][c2] + red[2][r][c2];
            h2[((size_t)b * NN + d0 + r) * FIN + c2] = acc[r];
        }
        const int lane = t & 63, wv = t >> 6;
        const float asv = as2[c2], adv = ad2[c2];
        #pragma unroll
        for (int r = 0; r < 4; ++r) {
            float s = acc[r] * asv, dd = acc[r] * adv;
            #pragma unroll
            for (int off = 32; off > 0; off >>= 1) {
                s += __shfl_down(s, off, 64);
                dd += __shfl_down(dd, off, 64);
            }
            if (lane == 0) { redS[r][wv] = s; redD[r][wv] = dd; }
        }
    }
    __syncthreads();
    if (t < 4) {
        a_src2[(size_t)b * NN + d0 + t] = redS[t][0] + redS[t][1];
        a_dst2[(size_t)b * NN + d0 + t] = redD[t][0] + redD[t][1];
    }
}

// ---------------- K3: layer-2 softmax + aggregate + bias --------------------
// 512 blocks x 512 thr; 4 dsts/block; srcs 4-way split (q), 4 FMA/load.
__global__ __launch_bounds__(512, 4)
void agg2_kernel(const float* __restrict__ h2, const float* __restrict__ a_src,
                 const float* __restrict__ a_dst, const float* __restrict__ b2,
                 float* __restrict__ out) {
    __shared__ float s_as[NN];
    __shared__ float s_ad[4];
    __shared__ float sp[4][NN];
    __shared__ float redm[4][2], reds[4][2];
    __shared__ float s_den[4];
    __shared__ float redA[3][4][FIN];       // 6 KB

    const int blk = blockIdx.x, t = threadIdx.x;
    const int b = blk & 7, d0 = (blk >> 3) * 4;

    if (t < NN) s_as[t] = a_src[(size_t)b * NN + t];
    if (t < 4) s_ad[t] = a_dst[(size_t)b * NN + d0 + t];
    __syncthreads();

    // softmax: 128-thread group per dst.
    const int d = t >> 7, l = t & 127, lane = t & 63, w = (t >> 6) & 1;
    const float adst = s_ad[d];
    float e0 = lrelu(s_as[l] + adst);
    float e1 = lrelu(s_as[l + 128] + adst);
    float mx = fmaxf(e0, e1);
    #pragma unroll
    for (int off = 32; off > 0; off >>= 1)
        mx = fmaxf(mx, __shfl_down(mx, off, 64));
    if (lane == 0) redm[d][w] = mx;
    __syncthreads();
    const float m = fmaxf(redm[d][0], redm[d][1]);
    float p0 = __expf(e0 - m), p1 = __expf(e1 - m);
    sp[d][l] = p0;
    sp[d][l + 128] = p1;
    float sum = p0 + p1;
    #pragma unroll
    for (int off = 32; off > 0; off >>= 1)
        sum += __shfl_down(sum, off, 64);
    if (lane == 0) reds[d][w] = sum;
    __syncthreads();
    if (t < 4) s_den[t] = reds[t][0] + reds[t][1] + 1e-16f;
    __syncthreads();

    // aggregation: q = src-quarter; all 4 dsts per thread -> 4 FMA per load.
    const int c = l, q = d;
    float a4[4] = {0.f, 0.f, 0.f, 0.f};
    const float* hb = h2 + ((size_t)(b * NN) + q * 64) * FIN + c;
    #pragma unroll 8
    for (int i = 0; i < 64; ++i) {
        float hv = hb[(size_t)i * FIN];
        int src = q * 64 + i;
        a4[0] = fmaf(sp[0][src], hv, a4[0]);
        a4[1] = fmaf(sp[1][src], hv, a4[1]);
        a4[2] = fmaf(sp[2][src], hv, a4[2]);
        a4[3] = fmaf(sp[3][src], hv, a4[3]);
    }
    if (q > 0) {
        #pragma unroll
        for (int j = 0; j < 4; ++j) redA[q - 1][j][c] = a4[j];
    }
    __syncthreads();
    if (q == 0) {
        #pragma unroll
        for (int j = 0; j < 4; ++j) {
            float v = a4[j] + redA[0][j][c] + redA[1][j][c] + redA[2][j][c];
            out[((size_t)b * NN + d0 + j) * FIN + c] = v / s_den[j] + b2[c];
        }
    }
}

// ---------------- launch -----------------------------------------------------
extern "C" void kernel_launch(void* const* d_in, const int* in_sizes, int n_in,
                              void* d_out, int out_size, void* d_ws, size_t ws_size,
                              hipStream_t stream) {
    const float* x   = (const float*)d_in[0];
    const float* W1  = (const float*)d_in[1];
    const float* as1 = (const float*)d_in[2];
    const float* ad1 = (const float*)d_in[3];
    const float* b1  = (const float*)d_in[4];
    const float* W2  = (const float*)d_in[5];
    const float* as2 = (const float*)d_in[6];
    const float* ad2 = (const float*)d_in[7];
    const float* b2  = (const float*)d_in[8];
    float* out = (float*)d_out;

    float* ws = (float*)d_ws;
    float* h1  = ws;                      // 8*256*512 = 1048576
    float* h2  = ws + 1048576;            // 262144
    float* aS1 = ws + 1310720;            // 8192
    float* aD1 = ws + 1318912;            // 8192
    float* aS2 = ws + 1327104;            // 2048
    float* aD2 = ws + 1329152;            // 2048

    gemm1_fused<<<512, 512, 0, stream>>>(x, W1, as1, ad1, h1, aS1, aD1);
    mid_fused<<<512, 512, 0, stream>>>(h1, aS1, aD1, b1, W2, as2, ad2, h2, aS2, aD2);
    agg2_kernel<<<512, 512, 0, stream>>>(h2, aS2, aD2, b2, out);
}